// Round 7
// baseline (78.596 us; speedup 1.0000x reference)
//
#include <hip/hip_runtime.h>

#define H_IN 4096
#define W_IN 4096
#define KH 15
#define KW 15
#define OH (H_IN - KH + 1)   // 4082
#define OW (W_IN - KW + 1)   // 4082

#define NJ 4                        // 16-col j-frags per wave
#define WROWS 16                    // output rows per wave-tile
#define WCOLS (16 * NJ)             // 64 output cols per wave-tile
#define SROWS (WROWS + KH - 1)      // 30 staged rows
#define SCH 10                      // 16B chunks per staged row (80 bf16 cols)
#define ROW_USH 88                  // stride = 11 granules (odd):
                                    // A-read class (3*(l&15)+(l>>4))%8 ->
                                    // 2/class per quarter-wave, 8/class per wave
#define WAVE_USH (SROWS * ROW_USH)  // 2640 ushort = 5280 B per wave
#define NTX 64                      // x tiles
#define NTY 256                     // y tiles
#define TPW 4                       // tiles per wave (consecutive y, same x)

typedef __attribute__((ext_vector_type(8))) short short8;   // MFMA A/B frag
typedef __attribute__((ext_vector_type(4))) float f32x4;    // MFMA C/D frag

__device__ __forceinline__ ushort f2bf(float f) {
    union { float f; uint32_t u; } v; v.f = f;
    uint32_t r = (v.u + 0x7FFFu + ((v.u >> 16) & 1u)) >> 16;  // RNE
    return (ushort)r;
}
__device__ __forceinline__ uint32_t pk2(float a, float b) {
    return (uint32_t)f2bf(a) | ((uint32_t)f2bf(b) << 16);
}

__global__ __launch_bounds__(256, 4)
void conv2d_mfma_wavetile(const float* __restrict__ X,
                          const float* __restrict__ Wt,
                          const float* __restrict__ Bias,
                          float* __restrict__ Out)
{
    __shared__ ushort s_w[KH * 64 * 8];      // 15360 B, persistent weight frags
    __shared__ ushort s_x[4 * WAVE_USH];     // 21120 B, 4 wave-private tiles

    const int tid = threadIdx.x;
    const int l = tid & 63;
    const int w = tid >> 6;

    // ---- build banded Toeplitz weight frags once; region is NEVER overwritten,
    //      so B-frags are re-read per kh (no 60-reg hoist -> no spill) ----
    // B[k][j] = w[kh][k-j]; lane l holds B[8*(l>>4)+u][l&15], u=0..7
    for (int idx = tid; idx < KH * 64; idx += 256) {
        int kh = idx >> 6, ll = idx & 63;
        int j = ll & 15, k0 = (ll >> 4) * 8;
        ushort* dst = &s_w[idx * 8];
#pragma unroll
        for (int u = 0; u < 8; ++u) {
            int kw = k0 + u - j;
            dst[u] = f2bf((kw >= 0 && kw < KW) ? Wt[kh * KW + kw] : 0.0f);
        }
    }
    __syncthreads();    // only block-wide barrier in the kernel

    ushort* const my = &s_x[w * WAVE_USH];
    const ushort* const abase = my + (l & 15) * ROW_USH + (l >> 4) * 8;
    const ushort* const bbase = &s_w[l * 8];
    const float b = Bias[0];

    const int gw  = blockIdx.x * 4 + w;     // global wave id, [0, 4096)
    const int tx  = gw >> 6;                // tile col
    const int ty0 = (gw & 63) * TPW;        // first tile row
    const int ox0 = tx * WCOLS;
    const bool xint = (ox0 + SCH * 8 <= W_IN);

#pragma unroll 1
    for (int t = 0; t < TPW; ++t) {
        const int iy0 = (ty0 + t) * WROWS;

        // ---- wave-private stage: 30 rows x 80 cols fp32 -> bf16 ----
#pragma unroll
        for (int it = 0; it < 5; ++it) {
            int idx = it * 64 + l;
            if (idx < SROWS * SCH) {
                int r = idx / SCH, q = idx % SCH;
                int gy = min(iy0 + r, H_IN - 1);
                const float* rp = X + (size_t)gy * W_IN;
                int gx = ox0 + q * 8;
                float4 va, vb;
                if (xint) {
                    va = *reinterpret_cast<const float4*>(rp + gx);
                    vb = *reinterpret_cast<const float4*>(rp + gx + 4);
                } else {
                    va.x = rp[min(gx + 0, W_IN - 1)];
                    va.y = rp[min(gx + 1, W_IN - 1)];
                    va.z = rp[min(gx + 2, W_IN - 1)];
                    va.w = rp[min(gx + 3, W_IN - 1)];
                    vb.x = rp[min(gx + 4, W_IN - 1)];
                    vb.y = rp[min(gx + 5, W_IN - 1)];
                    vb.z = rp[min(gx + 6, W_IN - 1)];
                    vb.w = rp[min(gx + 7, W_IN - 1)];
                }
                uint4 pk;
                pk.x = pk2(va.x, va.y);
                pk.y = pk2(va.z, va.w);
                pk.z = pk2(vb.x, vb.y);
                pk.w = pk2(vb.z, vb.w);
                *reinterpret_cast<uint4*>(&my[r * ROW_USH + q * 8]) = pk;
            }
        }
        // no barrier: region is wave-private, per-wave DS ordering suffices

        // ---- compute: per kh {1 B-read, 4 A-reads, 4 MFMAs} ----
        f32x4 acc[NJ];
#pragma unroll
        for (int j = 0; j < NJ; ++j) acc[j] = (f32x4){0.f, 0.f, 0.f, 0.f};

#pragma unroll
        for (int kh = 0; kh < KH; ++kh) {
            short8 bf = *reinterpret_cast<const short8*>(bbase + kh * 64 * 8);
#pragma unroll
            for (int j = 0; j < NJ; ++j) {
                short8 a = *reinterpret_cast<const short8*>(abase + kh * ROW_USH + j * 16);
                acc[j] = __builtin_amdgcn_mfma_f32_16x16x32_bf16(a, bf, acc[j], 0, 0, 0);
            }
        }

        // ---- store: C/D layout col=lane&15, row=(lane>>4)*4+r ----
        const int orow0 = iy0 + (l >> 4) * 4;
        const int ocol  = ox0 + (l & 15);
        if (iy0 + WROWS <= OH && ox0 + WCOLS <= OW) {
            float* op0 = &Out[(size_t)orow0 * OW + ocol];
#pragma unroll
            for (int j = 0; j < NJ; ++j) {
#pragma unroll
                for (int r = 0; r < 4; ++r)
                    op0[(size_t)r * OW + j * 16] = acc[j][r] + b;
            }
        } else {
#pragma unroll
            for (int j = 0; j < NJ; ++j) {
                int oc = ocol + j * 16;
                if (oc < OW) {
#pragma unroll
                    for (int r = 0; r < 4; ++r) {
                        int orow = orow0 + r;
                        if (orow < OH)
                            Out[(size_t)orow * OW + oc] = acc[j][r] + b;
                    }
                }
            }
        }
    }
}

extern "C" void kernel_launch(void* const* d_in, const int* in_sizes, int n_in,
                              void* d_out, int out_size, void* d_ws, size_t ws_size,
                              hipStream_t stream)
{
    const float* X    = (const float*)d_in[0];
    const float* Wt   = (const float*)d_in[1];
    const float* Bias = (const float*)d_in[2];
    float* Out        = (float*)d_out;

    // 16384 wave-tiles / (4 waves/block * 4 tiles/wave) = 1024 persistent blocks
    dim3 grid(NTX * NTY / (4 * TPW));
    dim3 block(256);
    hipLaunchKernelGGL(conv2d_mfma_wavetile, grid, block, 0, stream, X, Wt, Bias, Out);
}